// Round 6
// baseline (261.234 us; speedup 1.0000x reference)
//
#include <hip/hip_runtime.h>
#include <hip/hip_cooperative_groups.h>

namespace cg = cooperative_groups;

#define HW      4096      // 64*64
#define NC      256
#define NTB     24        // 3 tensors * 8 batches
#define TOPK    2048      // max(1, int(0.5 * 4096))
#define BLOCKS  1024
#define THREADS 256
#define TOTAL_THR (BLOCKS * THREADS)          // 262144
#define NVF4    (NTB * NC * HW / 4)           // 6291456 vf4 total
#define C_ITERS (NVF4 / TOTAL_THR)            // 24 vf4 per thread

typedef float vf4 __attribute__((ext_vector_type(4)));
typedef float vf2 __attribute__((ext_vector_type(2)));

// ===========================================================================
// Fused cooperative kernel: A (importance) -> sync -> B (select) -> sync ->
// C (apply). All phase math bitwise-identical to the proven 3-kernel version.
// ===========================================================================
__global__ __launch_bounds__(THREADS) void k_fused(const float* __restrict__ i0,
                                                   const float* __restrict__ i1,
                                                   const float* __restrict__ i2,
                                                   float* __restrict__ ws,
                                                   vf4* __restrict__ out) {
  cg::grid_group grid = cg::this_grid();

  // ---- Phase A: imp = mean_c |x|, sequential chain per hw (bitwise == np) --
  // 384 blocks' wave-0, 64 float4-chains per wave: 1 KB contiguous per load
  // instr, unroll-16 -> 16 KB in flight per wave (6.3 MB chip-wide).
  if (blockIdx.x < 384 && threadIdx.x < 64) {
    int chain = blockIdx.x * 64 + threadIdx.x;  // 0..24575 float4-chain id
    int tb  = chain >> 10;                      // 1024 hw4 per (t,b)
    int hw4 = chain & 1023;
    int t   = tb >> 3;
    const float* base = (t == 0 ? i0 : (t == 1 ? i1 : i2));
    const vf4* p = reinterpret_cast<const vf4*>(base + (size_t)(tb & 7) * NC * HW) + hw4;
    float s0 = 0.f, s1 = 0.f, s2 = 0.f, s3 = 0.f;
#pragma unroll 16
    for (int c = 0; c < NC; ++c) {
      vf4 v = p[c * (HW / 4)];
      s0 += fabsf(v.x);                         // program order per chain
      s1 += fabsf(v.y);
      s2 += fabsf(v.z);
      s3 += fabsf(v.w);
    }
    vf4 m;
    m.x = s0 * (1.0f / 256.0f);                 // exact pow2 == /256.0
    m.y = s1 * (1.0f / 256.0f);
    m.z = s2 * (1.0f / 256.0f);
    m.w = s3 * (1.0f / 256.0f);
    reinterpret_cast<vf4*>(ws)[chain] = m;
  }

  grid.sync();

  // ---- Phase B: one wave per (t,b): top-k threshold + stable mask ---------
  if (blockIdx.x < NTB && threadIdx.x < 64) {
    const int tb   = blockIdx.x;
    float* base    = ws + (size_t)tb * HW;
    const int lane = threadIdx.x;

    unsigned u[64];
    const vf4* p = reinterpret_cast<const vf4*>(base + lane * 64);
#pragma unroll
    for (int j = 0; j < 16; ++j) {
      vf4 v = p[j];
      u[4 * j + 0] = __float_as_uint(v.x);
      u[4 * j + 1] = __float_as_uint(v.y);
      u[4 * j + 2] = __float_as_uint(v.z);
      u[4 * j + 3] = __float_as_uint(v.w);
    }

    unsigned mx = 0u, mn = 0xFFFFFFFFu;
#pragma unroll
    for (int j = 0; j < 64; ++j) {
      mx = (u[j] > mx) ? u[j] : mx;
      mn = (u[j] < mn) ? u[j] : mn;
    }
#pragma unroll
    for (int off = 32; off > 0; off >>= 1) {
      unsigned ox = (unsigned)__shfl_xor((int)mx, off, 64);
      unsigned on = (unsigned)__shfl_xor((int)mn, off, 64);
      mx = (ox > mx) ? ox : mx;
      mn = (on < mn) ? on : mn;
    }

    unsigned lo = mn, hi = mx + 1u;
    while (hi - lo > 1u) {
      unsigned mid = lo + ((hi - lo) >> 1);
      int c = 0;
#pragma unroll
      for (int j = 0; j < 64; ++j) c += (u[j] >= mid);
#pragma unroll
      for (int off = 32; off > 0; off >>= 1) c += __shfl_xor(c, off, 64);
      if (c >= TOPK) lo = mid; else hi = mid;
    }
    const unsigned thr = lo;

    int eq = 0, gt = 0;
#pragma unroll
    for (int j = 0; j < 64; ++j) {
      eq += (u[j] == thr);
      gt += (u[j] > thr);
    }
    int g_tot = gt;
#pragma unroll
    for (int off = 32; off > 0; off >>= 1) g_tot += __shfl_xor(g_tot, off, 64);

    int incl = eq;
#pragma unroll
    for (int off = 1; off < 64; off <<= 1) {
      int n = __shfl_up(incl, off, 64);
      if (lane >= off) incl += n;
    }
    int r = incl - eq;
    const int needed = TOPK - g_tot;

    vf4* q = reinterpret_cast<vf4*>(base + lane * 64);
#pragma unroll
    for (int j = 0; j < 16; ++j) {
      float mv[4];
#pragma unroll
      for (int s = 0; s < 4; ++s) {
        unsigned x = u[4 * j + s];
        int e = (x == thr);
        mv[s] = (x > thr || (e && r < needed)) ? 1.f : 0.f;
        r += e;
      }
      vf4 m;
      m.x = mv[0]; m.y = mv[1]; m.z = mv[2]; m.w = mv[3];
      q[j] = m;
    }
  }

  grid.sync();

  // ---- Phase C: out = in * mask; cached loads (L3-resident re-read), nt
  // stores (don't evict input via write-allocate). 24 vf4/thread, 6 batches
  // of 4 independent loads in flight.
  {
    const int flat = blockIdx.x * THREADS + threadIdx.x;
    const vf4* mask = reinterpret_cast<const vf4*>(ws);
#pragma unroll
    for (int it = 0; it < C_ITERS / 4; ++it) {
      int idx[4];
      vf4 a[4], m[4];
#pragma unroll
      for (int q = 0; q < 4; ++q) {
        int i = flat + (it * 4 + q) * TOTAL_THR;
        idx[q] = i;
        int tb = i >> 18;                       // 2^18 vf4 per (t,b)
        int t  = tb >> 3;
        const vf4* src = (t == 0 ? (const vf4*)i0 : (t == 1 ? (const vf4*)i1 : (const vf4*)i2));
        a[q] = src[i - (t << 21)];              // 2^21 vf4 per tensor
        m[q] = mask[(tb << 10) | (i & 1023)];
      }
#pragma unroll
      for (int q = 0; q < 4; ++q) {
        vf4 r = a[q] * m[q];
        __builtin_nontemporal_store(r, &out[idx[q]]);
      }
    }
  }
}

// ===========================================================================
// Fallback 3-kernel path (exact R5 code) in case cooperative launch is
// rejected under graph capture.
// ===========================================================================
__global__ __launch_bounds__(256) void k_imp(const float* __restrict__ i0,
                                             const float* __restrict__ i1,
                                             const float* __restrict__ i2,
                                             float* __restrict__ imp) {
  int tid = blockIdx.x * 256 + threadIdx.x;
  int hw  = tid & (HW - 1);
  int tb  = tid >> 12;
  int t   = tb >> 3;
  const float* base = (t == 0 ? i0 : (t == 1 ? i1 : i2));
  const float* p = base + (size_t)(tb & 7) * NC * HW + hw;
  float s = 0.f;
#pragma unroll 32
  for (int c = 0; c < NC; ++c) s += fabsf(p[c * HW]);
  imp[tid] = s * (1.0f / 256.0f);
}

__global__ __launch_bounds__(64) void k_select(float* __restrict__ impmask) {
  const int tb   = blockIdx.x;
  float* base    = impmask + (size_t)tb * HW;
  const int lane = threadIdx.x;
  unsigned u[64];
  const vf4* p = reinterpret_cast<const vf4*>(base + lane * 64);
#pragma unroll
  for (int j = 0; j < 16; ++j) {
    vf4 v = p[j];
    u[4 * j + 0] = __float_as_uint(v.x);
    u[4 * j + 1] = __float_as_uint(v.y);
    u[4 * j + 2] = __float_as_uint(v.z);
    u[4 * j + 3] = __float_as_uint(v.w);
  }
  unsigned mx = 0u, mn = 0xFFFFFFFFu;
#pragma unroll
  for (int j = 0; j < 64; ++j) {
    mx = (u[j] > mx) ? u[j] : mx;
    mn = (u[j] < mn) ? u[j] : mn;
  }
#pragma unroll
  for (int off = 32; off > 0; off >>= 1) {
    unsigned ox = (unsigned)__shfl_xor((int)mx, off, 64);
    unsigned on = (unsigned)__shfl_xor((int)mn, off, 64);
    mx = (ox > mx) ? ox : mx;
    mn = (on < mn) ? on : mn;
  }
  unsigned lo = mn, hi = mx + 1u;
  while (hi - lo > 1u) {
    unsigned mid = lo + ((hi - lo) >> 1);
    int c = 0;
#pragma unroll
    for (int j = 0; j < 64; ++j) c += (u[j] >= mid);
#pragma unroll
    for (int off = 32; off > 0; off >>= 1) c += __shfl_xor(c, off, 64);
    if (c >= TOPK) lo = mid; else hi = mid;
  }
  const unsigned thr = lo;
  int eq = 0, gt = 0;
#pragma unroll
  for (int j = 0; j < 64; ++j) {
    eq += (u[j] == thr);
    gt += (u[j] > thr);
  }
  int g_tot = gt;
#pragma unroll
  for (int off = 32; off > 0; off >>= 1) g_tot += __shfl_xor(g_tot, off, 64);
  int incl = eq;
#pragma unroll
  for (int off = 1; off < 64; off <<= 1) {
    int n = __shfl_up(incl, off, 64);
    if (lane >= off) incl += n;
  }
  int r = incl - eq;
  const int needed = TOPK - g_tot;
  vf4* q = reinterpret_cast<vf4*>(base + lane * 64);
#pragma unroll
  for (int j = 0; j < 16; ++j) {
    float mv[4];
#pragma unroll
    for (int s = 0; s < 4; ++s) {
      unsigned x = u[4 * j + s];
      int e = (x == thr);
      mv[s] = (x > thr || (e && r < needed)) ? 1.f : 0.f;
      r += e;
    }
    vf4 m;
    m.x = mv[0]; m.y = mv[1]; m.z = mv[2]; m.w = mv[3];
    q[j] = m;
  }
}

__global__ __launch_bounds__(256) void k_apply(const vf4* __restrict__ i0,
                                               const vf4* __restrict__ i1,
                                               const vf4* __restrict__ i2,
                                               const vf4* __restrict__ mask,
                                               vf4* __restrict__ out) {
  int i = blockIdx.x * 256 + threadIdx.x;
  int hw4 = i & 1023;
  int tb  = i >> 18;
  int t   = tb >> 3;
  const vf4* src = (t == 0 ? i0 : (t == 1 ? i1 : i2));
  vf4 a = src[i - (t << 21)];
  vf4 m = mask[(tb << 10) | hw4];
  vf4 r = a * m;
  __builtin_nontemporal_store(r, &out[i]);
}

extern "C" void kernel_launch(void* const* d_in, const int* in_sizes, int n_in,
                              void* d_out, int out_size, void* d_ws, size_t ws_size,
                              hipStream_t stream) {
  const float* i0 = (const float*)d_in[0];
  const float* i1 = (const float*)d_in[1];
  const float* i2 = (const float*)d_in[2];
  float* ws = (float*)d_ws;          // 384 KB scratch: imp -> mask in place
  vf4* out = (vf4*)d_out;

  void* args[] = {(void*)&i0, (void*)&i1, (void*)&i2, (void*)&ws, (void*)&out};
  hipError_t err = hipLaunchCooperativeKernel((const void*)k_fused,
                                              dim3(BLOCKS), dim3(THREADS),
                                              args, 0, stream);
  if (err != hipSuccess) {
    // fallback: proven 3-kernel path (R5)
    k_imp<<<384, 256, 0, stream>>>(i0, i1, i2, ws);
    k_select<<<NTB, 64, 0, stream>>>(ws);
    k_apply<<<24576, 256, 0, stream>>>((const vf4*)i0, (const vf4*)i1,
                                       (const vf4*)i2, (const vf4*)ws, out);
  }
}

// Round 7
// 149.379 us; speedup vs baseline: 1.7488x; 1.7488x over previous
//
#include <hip/hip_runtime.h>

#define HW   4096      // 64*64
#define NC   256
#define NTB  24        // 3 tensors * 8 batches
#define TOPK 2048      // max(1, int(0.5 * 4096))

typedef float vf4 __attribute__((ext_vector_type(4)));

// ---------------------------------------------------------------------------
// Pass A: imp[tb][hw] = (sum_{c seq} |x[tb][c][hw]|) / 256  (bitwise == np).
// R5 version: scalar chain/thread, 384 blocks x 256, unroll-32.
// ---------------------------------------------------------------------------
__global__ __launch_bounds__(256) void k_imp(const float* __restrict__ i0,
                                             const float* __restrict__ i1,
                                             const float* __restrict__ i2,
                                             float* __restrict__ imp) {
  int tid = blockIdx.x * 256 + threadIdx.x;   // 0 .. 98303
  int hw  = tid & (HW - 1);
  int tb  = tid >> 12;                        // 0 .. 23
  int t   = tb >> 3;
  const float* base = (t == 0 ? i0 : (t == 1 ? i1 : i2));
  const float* p = base + (size_t)(tb & 7) * NC * HW + hw;
  float s = 0.f;
#pragma unroll 32
  for (int c = 0; c < NC; ++c) s += fabsf(p[c * HW]);
  imp[tid] = s * (1.0f / 256.0f);             // exact pow2 == /256.0
}

// ---------------------------------------------------------------------------
// Pass B: one wave per (t,b); all 4096 values in registers; binary search on
// uint bits; stable ties. Mask overwrites imp in place. (R5, absmax-0 proven.)
// ---------------------------------------------------------------------------
__global__ __launch_bounds__(64) void k_select(float* __restrict__ impmask) {
  const int tb   = blockIdx.x;
  float* base    = impmask + (size_t)tb * HW;
  const int lane = threadIdx.x;
  unsigned u[64];
  const vf4* p = reinterpret_cast<const vf4*>(base + lane * 64);
#pragma unroll
  for (int j = 0; j < 16; ++j) {
    vf4 v = p[j];
    u[4 * j + 0] = __float_as_uint(v.x);
    u[4 * j + 1] = __float_as_uint(v.y);
    u[4 * j + 2] = __float_as_uint(v.z);
    u[4 * j + 3] = __float_as_uint(v.w);
  }
  unsigned mx = 0u, mn = 0xFFFFFFFFu;
#pragma unroll
  for (int j = 0; j < 64; ++j) {
    mx = (u[j] > mx) ? u[j] : mx;
    mn = (u[j] < mn) ? u[j] : mn;
  }
#pragma unroll
  for (int off = 32; off > 0; off >>= 1) {
    unsigned ox = (unsigned)__shfl_xor((int)mx, off, 64);
    unsigned on = (unsigned)__shfl_xor((int)mn, off, 64);
    mx = (ox > mx) ? ox : mx;
    mn = (on < mn) ? on : mn;
  }
  unsigned lo = mn, hi = mx + 1u;
  while (hi - lo > 1u) {
    unsigned mid = lo + ((hi - lo) >> 1);
    int c = 0;
#pragma unroll
    for (int j = 0; j < 64; ++j) c += (u[j] >= mid);
#pragma unroll
    for (int off = 32; off > 0; off >>= 1) c += __shfl_xor(c, off, 64);
    if (c >= TOPK) lo = mid; else hi = mid;
  }
  const unsigned thr = lo;
  int eq = 0, gt = 0;
#pragma unroll
  for (int j = 0; j < 64; ++j) {
    eq += (u[j] == thr);
    gt += (u[j] > thr);
  }
  int g_tot = gt;
#pragma unroll
  for (int off = 32; off > 0; off >>= 1) g_tot += __shfl_xor(g_tot, off, 64);
  int incl = eq;
#pragma unroll
  for (int off = 1; off < 64; off <<= 1) {
    int n = __shfl_up(incl, off, 64);
    if (lane >= off) incl += n;
  }
  int r = incl - eq;
  const int needed = TOPK - g_tot;
  vf4* q = reinterpret_cast<vf4*>(base + lane * 64);
#pragma unroll
  for (int j = 0; j < 16; ++j) {
    float mv[4];
#pragma unroll
    for (int s = 0; s < 4; ++s) {
      unsigned x = u[4 * j + s];
      int e = (x == thr);
      mv[s] = (x > thr || (e && r < needed)) ? 1.f : 0.f;
      r += e;
    }
    vf4 m;
    m.x = mv[0]; m.y = mv[1]; m.z = mv[2]; m.w = mv[3];
    q[j] = m;
  }
}

// ---------------------------------------------------------------------------
// Pass C ×5 PROBE: grid-stride 2048 blocks x 256 thr, CACHED input loads
// (L3-resident, confirmed by R6 fused FETCH=99MB), nt stores. The work is
// repeated REPS times writing identical values -> output exact; memory
// clobbers between reps stop CSE/DSE from collapsing the repetitions.
// Top-5 rocprof row for this kernel gives C's true per-rep duration and
// whether its reads stay cache-resident (FETCH ~20MB) or not (~480MB).
// ---------------------------------------------------------------------------
#define APPLY_BLOCKS 2048
#define APPLY_STRIDE (APPLY_BLOCKS * 256)
#define APPLY_REPS   5
__global__ __launch_bounds__(256) void k_apply5(const vf4* __restrict__ i0,
                                                const vf4* __restrict__ i1,
                                                const vf4* __restrict__ i2,
                                                const vf4* __restrict__ mask,
                                                vf4* __restrict__ out) {
  const int base_idx = blockIdx.x * 256 + threadIdx.x;
  // total vf4 = 24*256*1024 = 6291456 = APPLY_STRIDE * 12 exactly
  for (int rep = 0; rep < APPLY_REPS; ++rep) {
#pragma unroll
    for (int it = 0; it < 3; ++it) {
      int idx[4];
      vf4 a[4], m[4];
#pragma unroll
      for (int q = 0; q < 4; ++q) {
        int i = base_idx + (it * 4 + q) * APPLY_STRIDE;
        idx[q] = i;
        int tb = i >> 18;                       // 2^18 vf4 per (t,b)
        int t  = tb >> 3;
        const vf4* src = (t == 0 ? i0 : (t == 1 ? i1 : i2));
        a[q] = src[i - (t << 21)];              // cached read (L3-resident)
        m[q] = mask[(tb << 10) | (i & 1023)];
      }
#pragma unroll
      for (int q = 0; q < 4; ++q) {
        vf4 r = a[q] * m[q];
        __builtin_nontemporal_store(r, &out[idx[q]]);
      }
    }
    asm volatile("" ::: "memory");   // keep each rep's loads+stores live
  }
}

extern "C" void kernel_launch(void* const* d_in, const int* in_sizes, int n_in,
                              void* d_out, int out_size, void* d_ws, size_t ws_size,
                              hipStream_t stream) {
  const float* i0 = (const float*)d_in[0];
  const float* i1 = (const float*)d_in[1];
  const float* i2 = (const float*)d_in[2];
  float* imp = (float*)d_ws;   // 384 KB scratch: imp -> mask in place

  k_imp<<<384, 256, 0, stream>>>(i0, i1, i2, imp);
  k_select<<<NTB, 64, 0, stream>>>(imp);
  k_apply5<<<APPLY_BLOCKS, 256, 0, stream>>>((const vf4*)i0, (const vf4*)i1,
                                             (const vf4*)i2, (const vf4*)imp,
                                             (vf4*)d_out);
}

// Round 8
// 70.679 us; speedup vs baseline: 3.6960x; 2.1135x over previous
//
#include <hip/hip_runtime.h>

#define HW   4096      // 64*64
#define NC   256
#define NTB  24        // 3 tensors * 8 batches
#define TOPK 2048      // max(1, int(0.5 * 4096))

typedef float vf4 __attribute__((ext_vector_type(4)));

// ---------------------------------------------------------------------------
// Pass A x5 PROBE: imp[tb][hw] = (sum_{c seq} |x|)/256, bitwise == np order.
// R5 geometry (scalar chain/thread, 384 blocks x 256, unroll-32) repeated 5x
// writing identical values (clobber stops CSE/DSE — validated in R7's C-probe).
// Rep0 reads HBM-cold, reps1-4 read L3-warm: row dur + FETCH split
// "A is HBM-bound" vs "A is issue/latency-bound".
// ---------------------------------------------------------------------------
#define IMP_REPS 5
__global__ __launch_bounds__(256) void k_imp5(const float* __restrict__ i0,
                                              const float* __restrict__ i1,
                                              const float* __restrict__ i2,
                                              float* __restrict__ imp) {
  int tid = blockIdx.x * 256 + threadIdx.x;   // 0 .. 98303
  int hw  = tid & (HW - 1);
  int tb  = tid >> 12;                        // 0 .. 23
  int t   = tb >> 3;
  const float* base = (t == 0 ? i0 : (t == 1 ? i1 : i2));
  const float* p = base + (size_t)(tb & 7) * NC * HW + hw;
  for (int rep = 0; rep < IMP_REPS; ++rep) {
    float s = 0.f;
#pragma unroll 32
    for (int c = 0; c < NC; ++c) s += fabsf(p[c * HW]);  // program order per chain
    imp[tid] = s * (1.0f / 256.0f);           // exact pow2 == /256.0
    asm volatile("" ::: "memory");            // keep each rep's loads+store live
  }
}

// ---------------------------------------------------------------------------
// Pass B: one wave per (t,b); all 4096 values in registers; binary search on
// uint bits; stable ties. Mask overwrites imp in place. (absmax-0 proven.)
// ---------------------------------------------------------------------------
__global__ __launch_bounds__(64) void k_select(float* __restrict__ impmask) {
  const int tb   = blockIdx.x;
  float* base    = impmask + (size_t)tb * HW;
  const int lane = threadIdx.x;
  unsigned u[64];
  const vf4* p = reinterpret_cast<const vf4*>(base + lane * 64);
#pragma unroll
  for (int j = 0; j < 16; ++j) {
    vf4 v = p[j];
    u[4 * j + 0] = __float_as_uint(v.x);
    u[4 * j + 1] = __float_as_uint(v.y);
    u[4 * j + 2] = __float_as_uint(v.z);
    u[4 * j + 3] = __float_as_uint(v.w);
  }
  unsigned mx = 0u, mn = 0xFFFFFFFFu;
#pragma unroll
  for (int j = 0; j < 64; ++j) {
    mx = (u[j] > mx) ? u[j] : mx;
    mn = (u[j] < mn) ? u[j] : mn;
  }
#pragma unroll
  for (int off = 32; off > 0; off >>= 1) {
    unsigned ox = (unsigned)__shfl_xor((int)mx, off, 64);
    unsigned on = (unsigned)__shfl_xor((int)mn, off, 64);
    mx = (ox > mx) ? ox : mx;
    mn = (on < mn) ? on : mn;
  }
  unsigned lo = mn, hi = mx + 1u;
  while (hi - lo > 1u) {
    unsigned mid = lo + ((hi - lo) >> 1);
    int c = 0;
#pragma unroll
    for (int j = 0; j < 64; ++j) c += (u[j] >= mid);
#pragma unroll
    for (int off = 32; off > 0; off >>= 1) c += __shfl_xor(c, off, 64);
    if (c >= TOPK) lo = mid; else hi = mid;
  }
  const unsigned thr = lo;
  int eq = 0, gt = 0;
#pragma unroll
  for (int j = 0; j < 64; ++j) {
    eq += (u[j] == thr);
    gt += (u[j] > thr);
  }
  int g_tot = gt;
#pragma unroll
  for (int off = 32; off > 0; off >>= 1) g_tot += __shfl_xor(g_tot, off, 64);
  int incl = eq;
#pragma unroll
  for (int off = 1; off < 64; off <<= 1) {
    int n = __shfl_up(incl, off, 64);
    if (lane >= off) incl += n;
  }
  int r = incl - eq;
  const int needed = TOPK - g_tot;
  vf4* q = reinterpret_cast<vf4*>(base + lane * 64);
#pragma unroll
  for (int j = 0; j < 16; ++j) {
    float mv[4];
#pragma unroll
    for (int s = 0; s < 4; ++s) {
      unsigned x = u[4 * j + s];
      int e = (x == thr);
      mv[s] = (x > thr || (e && r < needed)) ? 1.f : 0.f;
      r += e;
    }
    vf4 m;
    m.x = mv[0]; m.y = mv[1]; m.z = mv[2]; m.w = mv[3];
    q[j] = m;
  }
}

// ---------------------------------------------------------------------------
// Pass C (probe-validated, 1 rep): grid-stride 2048 blocks x 256, CACHED
// input loads (L3-resident, R6/R7-confirmed), nt stores. ~23 us measured.
// ---------------------------------------------------------------------------
#define APPLY_BLOCKS 2048
#define APPLY_STRIDE (APPLY_BLOCKS * 256)
__global__ __launch_bounds__(256) void k_apply(const vf4* __restrict__ i0,
                                               const vf4* __restrict__ i1,
                                               const vf4* __restrict__ i2,
                                               const vf4* __restrict__ mask,
                                               vf4* __restrict__ out) {
  const int base_idx = blockIdx.x * 256 + threadIdx.x;
  // total vf4 = 24*256*1024 = 6291456 = APPLY_STRIDE * 12 exactly
#pragma unroll
  for (int it = 0; it < 3; ++it) {
    int idx[4];
    vf4 a[4], m[4];
#pragma unroll
    for (int q = 0; q < 4; ++q) {
      int i = base_idx + (it * 4 + q) * APPLY_STRIDE;
      idx[q] = i;
      int tb = i >> 18;                       // 2^18 vf4 per (t,b)
      int t  = tb >> 3;
      const vf4* src = (t == 0 ? i0 : (t == 1 ? i1 : i2));
      a[q] = src[i - (t << 21)];              // cached read (L3-resident)
      m[q] = mask[(tb << 10) | (i & 1023)];
    }
#pragma unroll
    for (int q = 0; q < 4; ++q) {
      vf4 r = a[q] * m[q];
      __builtin_nontemporal_store(r, &out[idx[q]]);
    }
  }
}

extern "C" void kernel_launch(void* const* d_in, const int* in_sizes, int n_in,
                              void* d_out, int out_size, void* d_ws, size_t ws_size,
                              hipStream_t stream) {
  const float* i0 = (const float*)d_in[0];
  const float* i1 = (const float*)d_in[1];
  const float* i2 = (const float*)d_in[2];
  float* imp = (float*)d_ws;   // 384 KB scratch: imp -> mask in place

  k_imp5<<<384, 256, 0, stream>>>(i0, i1, i2, imp);
  k_select<<<NTB, 64, 0, stream>>>(imp);
  k_apply<<<APPLY_BLOCKS, 256, 0, stream>>>((const vf4*)i0, (const vf4*)i1,
                                            (const vf4*)i2, (const vf4*)imp,
                                            (vf4*)d_out);
}